// Round 19
// baseline (442.923 us; speedup 1.0000x reference)
//
#include <hip/hip_runtime.h>
#include <math.h>

// N=100000 nodes, E=1600000 edges, features 128 -> 64 -> 64 -> 1.
// R19 = R18 + int4-vectorized edge streams in k_build_csr/k_hist.
// R18 counters: build_csr VALU 4%, BW 23%, occ 80% -> latency-bound on the
// per-edge atomic chain (load dst -> atomicAdd(ret) -> dependent store).
// 4 edges/thread/iter = 4 independent chains in flight + dwordx4 loads.
// NOTE: __launch_bounds__(256,4) is 0-for-4 on this harness — do not use.
// gemm2 K-loop needs `#pragma unroll 2` (full unroll -> 256 VGPR, occ 9%).
#define NN 100000
#define NE 1600000
#define NSHARD 8
#define SHARD_W (NN / NSHARD)   // 12500 exactly

// bf16 helpers (manual, round-to-nearest-even; intermediates only)
__device__ inline unsigned f2bf(float f) {
    unsigned u = __float_as_uint(f);
    u += 0x7FFFu + ((u >> 16) & 1u);
    return u >> 16;
}
__device__ inline float bflo(unsigned v) { return __uint_as_float(v << 16); }
__device__ inline float bfhi(unsigned v) { return __uint_as_float(v & 0xFFFF0000u); }

// ---------------------------------------------------------------------------
// CSR build: deg histogram -> block sums -> scan -> rowptr/cursor -> scatter.
// ---------------------------------------------------------------------------
__global__ void k_zero_deg(int* __restrict__ deg) {
    int i = blockIdx.x * 256 + threadIdx.x;
    if (i < NN) deg[i] = 0;
}

// 4 edges per thread (NE divisible by 4): 4 independent atomics in flight.
__global__ void k_hist(const int4* __restrict__ dst4, int* __restrict__ deg) {
    int i = blockIdx.x * 256 + threadIdx.x;
    if (i < NE / 4) {
        int4 d = dst4[i];
        atomicAdd(&deg[d.x], 1);
        atomicAdd(&deg[d.y], 1);
        atomicAdd(&deg[d.z], 1);
        atomicAdd(&deg[d.w], 1);
    }
}

__global__ void k_bsum(const int* __restrict__ deg, int* __restrict__ bsums) {
    __shared__ int s[256];
    int t = threadIdx.x;
    int i = blockIdx.x * 256 + t;
    s[t] = (i < NN) ? deg[i] : 0;
    __syncthreads();
    for (int off = 128; off > 0; off >>= 1) {
        if (t < off) s[t] += s[t + off];
        __syncthreads();
    }
    if (t == 0) bsums[blockIdx.x] = s[0];
}

// single block of 512 threads scans the 391 block sums (exclusive)
__global__ void k_scan512(const int* __restrict__ bsums, int* __restrict__ bscan) {
    __shared__ int s[512];
    int t = threadIdx.x;
    int v = (t < 391) ? bsums[t] : 0;
    s[t] = v;
    __syncthreads();
    for (int off = 1; off < 512; off <<= 1) {
        int x = (t >= off) ? s[t - off] : 0;
        __syncthreads();
        s[t] += x;
        __syncthreads();
    }
    bscan[t] = s[t] - v;  // exclusive
}

__global__ void k_rowptr(const int* __restrict__ deg, const int* __restrict__ bscan,
                         int* __restrict__ rowptr, int* __restrict__ cursor,
                         float* __restrict__ dis) {
    __shared__ int s[256];
    int t = threadIdx.x;
    int i = blockIdx.x * 256 + t;
    int d = (i < NN) ? deg[i] : 0;
    s[t] = d;
    __syncthreads();
    for (int off = 1; off < 256; off <<= 1) {
        int x = (t >= off) ? s[t - off] : 0;
        __syncthreads();
        s[t] += x;
        __syncthreads();
    }
    if (i < NN) {
        int rp = bscan[blockIdx.x] + s[t] - d;  // exclusive global prefix
        rowptr[i] = rp;
        cursor[i] = rp;
        dis[i] = rsqrtf((float)(d + 1));  // +1 self-loop; deg>=1 always
    }
    if (i == 0) rowptr[NN] = NE;
}

// XCD-sharded scatter; int4 edge loads give 4 independent atomic->store
// chains per thread-iteration (R18 was 1 -> latency-bound).
__global__ __launch_bounds__(256) void k_build_csr(
    const int4* __restrict__ src4, const int4* __restrict__ dst4,
    int* __restrict__ cursor, int* __restrict__ csr) {
    int shard = blockIdx.x & 7;
    int bsh = blockIdx.x >> 3;
    int stride = (gridDim.x >> 3) * 256;
    int lo = shard * SHARD_W;
    int hi = lo + SHARD_W;
    const int NE4 = NE / 4;
    for (int i = bsh * 256 + threadIdx.x; i < NE4; i += stride) {
        int4 d = dst4[i];
        int4 s = src4[i];
        if (d.x >= lo && d.x < hi) { int p = atomicAdd(&cursor[d.x], 1); csr[p] = s.x; }
        if (d.y >= lo && d.y < hi) { int p = atomicAdd(&cursor[d.y], 1); csr[p] = s.y; }
        if (d.z >= lo && d.z < hi) { int p = atomicAdd(&cursor[d.z], 1); csr[p] = s.z; }
        if (d.w >= lo && d.w < hi) { int p = atomicAdd(&cursor[d.w], 1); csr[p] = s.w; }
    }
}

// ---------------------------------------------------------------------------
// GEMM layer 1: tsb[row][c] = bf16( (sum_k x[row][k]*W[k][c]) * dis[row] )
// 64 rows x 64 cols per block; thread = 4 rows x 4 cols register tile.
// W and x staged as packed bf16 PAIRS in LDS (one pass, one barrier).
// ---------------------------------------------------------------------------
__global__ __launch_bounds__(256) void k_gemm1(
    const float* __restrict__ x, const float* __restrict__ W,
    const float* __restrict__ dis, unsigned short* __restrict__ tsb) {
    __shared__ unsigned Wsb[128 * 32];
    __shared__ unsigned xsb[64 * 66];
    int t = threadIdx.x;
    int row0 = blockIdx.x * 64;
    for (int i = t; i < 128 * 32; i += 256) {
        int k = i >> 5, c2 = i & 31;
        float2 wv = *(const float2*)&W[k * 64 + 2 * c2];
        Wsb[i] = f2bf(wv.x) | (f2bf(wv.y) << 16);
    }
    for (int i = t; i < 64 * 64; i += 256) {
        int r = i >> 6, k2 = i & 63;
        int gr = row0 + r;
        unsigned p = 0u;
        if (gr < NN) {
            float2 xv = *(const float2*)&x[gr * 128 + 2 * k2];
            p = f2bf(xv.x) | (f2bf(xv.y) << 16);
        }
        xsb[r * 66 + k2] = p;
    }
    __syncthreads();
    int cg = t & 15, rg = t >> 4;
    int col = cg * 4;
    float4 acc0 = {0, 0, 0, 0}, acc1 = {0, 0, 0, 0}, acc2 = {0, 0, 0, 0}, acc3 = {0, 0, 0, 0};
    for (int k2 = 0; k2 < 64; ++k2) {
        uint2 wa = *(const uint2*)&Wsb[(2 * k2) * 32 + cg * 2];
        uint2 wb = *(const uint2*)&Wsb[(2 * k2 + 1) * 32 + cg * 2];
        float wa0 = bflo(wa.x), wa1 = bfhi(wa.x), wa2 = bflo(wa.y), wa3 = bfhi(wa.y);
        float wb0 = bflo(wb.x), wb1 = bfhi(wb.x), wb2 = bflo(wb.y), wb3 = bfhi(wb.y);
        unsigned xp0 = xsb[(rg * 4 + 0) * 66 + k2];
        unsigned xp1 = xsb[(rg * 4 + 1) * 66 + k2];
        unsigned xp2 = xsb[(rg * 4 + 2) * 66 + k2];
        unsigned xp3 = xsb[(rg * 4 + 3) * 66 + k2];
        float xl, xh;
        xl = bflo(xp0); xh = bfhi(xp0);
        acc0.x += xl * wa0 + xh * wb0; acc0.y += xl * wa1 + xh * wb1;
        acc0.z += xl * wa2 + xh * wb2; acc0.w += xl * wa3 + xh * wb3;
        xl = bflo(xp1); xh = bfhi(xp1);
        acc1.x += xl * wa0 + xh * wb0; acc1.y += xl * wa1 + xh * wb1;
        acc1.z += xl * wa2 + xh * wb2; acc1.w += xl * wa3 + xh * wb3;
        xl = bflo(xp2); xh = bfhi(xp2);
        acc2.x += xl * wa0 + xh * wb0; acc2.y += xl * wa1 + xh * wb1;
        acc2.z += xl * wa2 + xh * wb2; acc2.w += xl * wa3 + xh * wb3;
        xl = bflo(xp3); xh = bfhi(xp3);
        acc3.x += xl * wa0 + xh * wb0; acc3.y += xl * wa1 + xh * wb1;
        acc3.z += xl * wa2 + xh * wb2; acc3.w += xl * wa3 + xh * wb3;
    }
    float4 accs[4] = {acc0, acc1, acc2, acc3};
#pragma unroll
    for (int r = 0; r < 4; ++r) {
        int row = row0 + rg * 4 + r;
        if (row < NN) {
            float dv = dis[row];
            float4 a = accs[r];
            uint2 p;
            p.x = f2bf(a.x * dv) | (f2bf(a.y * dv) << 16);
            p.y = f2bf(a.z * dv) | (f2bf(a.w * dv) << 16);
            *(uint2*)&tsb[row * 64 + col] = p;
        }
    }
}

#define FMA4(acc, xv)                                              \
    acc.x += xv.x * w0.x + xv.y * w1.x + xv.z * w2.x + xv.w * w3.x; \
    acc.y += xv.x * w0.y + xv.y * w1.y + xv.z * w2.y + xv.w * w3.y; \
    acc.z += xv.x * w0.z + xv.y * w1.z + xv.z * w2.z + xv.w * w3.z; \
    acc.w += xv.x * w0.w + xv.y * w1.w + xv.z * w2.w + xv.w * w3.w;

// GEMM layer 2: reads bf16 h, writes bf16 ts. K=64.
// K-loop capped at unroll 2: full unroll balloons to 256 VGPR (R13).
__global__ __launch_bounds__(256) void k_gemm2(
    const unsigned short* __restrict__ hb, const float* __restrict__ W,
    const float* __restrict__ dis, unsigned short* __restrict__ tsb) {
    __shared__ float Ws[64 * 64];
    __shared__ float hs[64 * 68];
    int t = threadIdx.x;
    int row0 = blockIdx.x * 64;
    for (int i = t; i < 64 * 64; i += 256) Ws[i] = W[i];
    const unsigned* hb32 = (const unsigned*)hb;  // 2 bf16 per word, row stride 32
    for (int i = t; i < 64 * 32; i += 256) {
        int r = i >> 5, c2 = i & 31;
        int gr = row0 + r;
        unsigned v = (gr < NN) ? hb32[gr * 32 + c2] : 0u;
        hs[r * 68 + 2 * c2] = bflo(v);
        hs[r * 68 + 2 * c2 + 1] = bfhi(v);
    }
    __syncthreads();
    int cg = t & 15, rg = t >> 4;
    int col = cg * 4;
    float4 acc0 = {0, 0, 0, 0}, acc1 = {0, 0, 0, 0}, acc2 = {0, 0, 0, 0}, acc3 = {0, 0, 0, 0};
#pragma unroll 2
    for (int k = 0; k < 64; k += 4) {
        float4 w0 = *(const float4*)&Ws[(k + 0) * 64 + col];
        float4 w1 = *(const float4*)&Ws[(k + 1) * 64 + col];
        float4 w2 = *(const float4*)&Ws[(k + 2) * 64 + col];
        float4 w3 = *(const float4*)&Ws[(k + 3) * 64 + col];
        float4 x0 = *(const float4*)&hs[(rg * 4 + 0) * 68 + k];
        float4 x1 = *(const float4*)&hs[(rg * 4 + 1) * 68 + k];
        float4 x2 = *(const float4*)&hs[(rg * 4 + 2) * 68 + k];
        float4 x3 = *(const float4*)&hs[(rg * 4 + 3) * 68 + k];
        FMA4(acc0, x0) FMA4(acc1, x1) FMA4(acc2, x2) FMA4(acc3, x3)
    }
    float4 accs[4] = {acc0, acc1, acc2, acc3};
#pragma unroll
    for (int r = 0; r < 4; ++r) {
        int row = row0 + rg * 4 + r;
        if (row < NN) {
            float dv = dis[row];
            float4 a = accs[r];
            uint2 p;
            p.x = f2bf(a.x * dv) | (f2bf(a.y * dv) << 16);
            p.y = f2bf(a.z * dv) | (f2bf(a.w * dv) << 16);
            *(uint2*)&tsb[row * 64 + col] = p;
        }
    }
}

// ---------------------------------------------------------------------------
// Fused aggregation + dis scale + bias + ReLU, bf16 rows (128 B each).
// One 64-lane wave per node; QUARTER-wave (16 lanes x 8B) per edge -> 4
// edges in flight per load instruction. lane = feature QUAD (uint2 = 4 bf16).
// f32 accumulation; quads combined via shfl_xor(16) + shfl_xor(32).
// ---------------------------------------------------------------------------
__global__ __launch_bounds__(256) void k_agg_relu(
    const unsigned short* __restrict__ tsb, const int* __restrict__ rowptr,
    const int* __restrict__ csr, const float* __restrict__ dis,
    const float* __restrict__ b, unsigned short* __restrict__ hb) {
    int node = blockIdx.x * 4 + (threadIdx.x >> 6);
    if (node >= NN) return;
    int lane = threadIdx.x & 63;
    int q = lane >> 4;    // quarter 0..3
    int fl = lane & 15;   // feature quad: features 4*fl .. 4*fl+3
    const uint2* ts64 = (const uint2*)tsb;  // row stride 16 uint2
    float a0 = 0.f, a1 = 0.f, a2 = 0.f, a3 = 0.f;
    if (q == 0) {  // self-loop term, added once
        uint2 v = ts64[node * 16 + fl];
        a0 += bflo(v.x); a1 += bfhi(v.x); a2 += bflo(v.y); a3 += bfhi(v.y);
    }
    int e = rowptr[node] + q, end = rowptr[node + 1];
    // per-quarter stride 4; unroll 2 -> 8 edges in flight per wave
    for (; e + 4 < end; e += 8) {
        int s0 = csr[e];
        int s1 = csr[e + 4];
        uint2 v0 = ts64[s0 * 16 + fl];
        uint2 v1 = ts64[s1 * 16 + fl];
        a0 += bflo(v0.x) + bflo(v1.x);
        a1 += bfhi(v0.x) + bfhi(v1.x);
        a2 += bflo(v0.y) + bflo(v1.y);
        a3 += bfhi(v0.y) + bfhi(v1.y);
    }
    if (e < end) {
        uint2 v = ts64[csr[e] * 16 + fl];
        a0 += bflo(v.x); a1 += bfhi(v.x); a2 += bflo(v.y); a3 += bfhi(v.y);
    }
    a0 += __shfl_xor(a0, 16); a1 += __shfl_xor(a1, 16);
    a2 += __shfl_xor(a2, 16); a3 += __shfl_xor(a3, 16);
    a0 += __shfl_xor(a0, 32); a1 += __shfl_xor(a1, 32);
    a2 += __shfl_xor(a2, 32); a3 += __shfl_xor(a3, 32);
    if (q == 0) {
        float dv = dis[node];
        float v0 = fmaxf(a0 * dv + b[4 * fl + 0], 0.f);
        float v1 = fmaxf(a1 * dv + b[4 * fl + 1], 0.f);
        float v2 = fmaxf(a2 * dv + b[4 * fl + 2], 0.f);
        float v3 = fmaxf(a3 * dv + b[4 * fl + 3], 0.f);
        uint2 p;
        p.x = f2bf(v0) | (f2bf(v1) << 16);
        p.y = f2bf(v2) | (f2bf(v3) << 16);
        ((uint2*)hb)[node * 16 + fl] = p;
    }
}

// ---------------------------------------------------------------------------
// Layer 3 projection: t3[row] = dot(h_bf16[row], W3) * dis[row]   (f32 out)
// ---------------------------------------------------------------------------
__global__ void k_gemm3(const unsigned short* __restrict__ hb, const float* __restrict__ W3,
                        const float* __restrict__ dis, float* __restrict__ t3) {
    __shared__ float Ws[64];
    if (threadIdx.x < 64) Ws[threadIdx.x] = W3[threadIdx.x];
    __syncthreads();
    int row = blockIdx.x * 256 + threadIdx.x;
    if (row >= NN) return;
    const uint4* hp = (const uint4*)(hb + row * 64);  // 8 x uint4 = 128 B
    float acc = 0.f;
#pragma unroll
    for (int k = 0; k < 8; ++k) {
        uint4 v = hp[k];
        acc += bflo(v.x) * Ws[8 * k + 0] + bfhi(v.x) * Ws[8 * k + 1]
             + bflo(v.y) * Ws[8 * k + 2] + bfhi(v.y) * Ws[8 * k + 3]
             + bflo(v.z) * Ws[8 * k + 4] + bfhi(v.z) * Ws[8 * k + 5]
             + bflo(v.w) * Ws[8 * k + 6] + bfhi(v.w) * Ws[8 * k + 7];
    }
    t3[row] = acc * dis[row];
}

// Fused layer-3 aggregation + sigmoid. One thread per node, scalar gathers.
__global__ void k_out(const float* __restrict__ t3, const int* __restrict__ rowptr,
                      const int* __restrict__ csr, const float* __restrict__ dis,
                      const float* __restrict__ b3, float* __restrict__ out) {
    int i = blockIdx.x * 256 + threadIdx.x;
    if (i >= NN) return;
    float acc = t3[i];
    float acc1 = 0.f;
    int e = rowptr[i], end = rowptr[i + 1];
    for (; e + 2 <= end; e += 2) {
        acc += t3[csr[e]];
        acc1 += t3[csr[e + 1]];
    }
    if (e < end) acc += t3[csr[e]];
    float z = (acc + acc1) * dis[i] + b3[0];
    out[i] = 1.f / (1.f + __expf(-z));
}

// ---------------------------------------------------------------------------
extern "C" void kernel_launch(void* const* d_in, const int* in_sizes, int n_in,
                              void* d_out, int out_size, void* d_ws, size_t ws_size,
                              hipStream_t stream) {
    const float* x  = (const float*)d_in[0];   // N x 128
    const float* W1 = (const float*)d_in[1];   // 128 x 64
    const float* b1 = (const float*)d_in[2];   // 64
    const float* W2 = (const float*)d_in[3];   // 64 x 64
    const float* b2 = (const float*)d_in[4];   // 64
    const float* W3 = (const float*)d_in[5];   // 64 x 1
    const float* b3 = (const float*)d_in[6];   // 1
    const int*   ei = (const int*)d_in[7];     // 2 x E
    const int* src = ei;
    const int* dst = ei + NE;
    float* out = (float*)d_out;

    // Workspace layout
    unsigned short* TSB = (unsigned short*)d_ws;          // N*64 bf16 (ts)
    unsigned short* HB  = TSB + (size_t)NN * 64;          // N*64 bf16 (h)
    float* dis    = (float*)(HB + (size_t)NN * 64);       // N
    float* t3     = dis + NN;                             // N
    int*   deg    = (int*)(t3 + NN);                      // N
    int*   rowptr = deg + NN;                             // N+1 (+pad)
    int*   cursor = rowptr + NN + 8;                      // N
    int*   bsums  = cursor + NN;                          // 512
    int*   bscan  = bsums + 512;                          // 512
    int*   csr    = bscan + 512;                          // E

    const int nbN = (NN + 255) / 256;   // 391
    const int nbE4 = (NE / 4 + 255) / 256;  // 1563
    const int nbG = (NN + 63) / 64;     // 1563
    const int nbA = (NN + 3) / 4;       // 25000

    // CSR build + normalization
    k_zero_deg<<<nbN, 256, 0, stream>>>(deg);
    k_hist<<<nbE4, 256, 0, stream>>>((const int4*)dst, deg);
    k_bsum<<<nbN, 256, 0, stream>>>(deg, bsums);
    k_scan512<<<1, 512, 0, stream>>>(bsums, bscan);
    k_rowptr<<<nbN, 256, 0, stream>>>(deg, bscan, rowptr, cursor, dis);
    k_build_csr<<<2048, 256, 0, stream>>>((const int4*)src, (const int4*)dst, cursor, csr);

    // Layer 1
    k_gemm1<<<nbG, 256, 0, stream>>>(x, W1, dis, TSB);
    k_agg_relu<<<nbA, 256, 0, stream>>>(TSB, rowptr, csr, dis, b1, HB);

    // Layer 2
    k_gemm2<<<nbG, 256, 0, stream>>>(HB, W2, dis, TSB);
    k_agg_relu<<<nbA, 256, 0, stream>>>(TSB, rowptr, csr, dis, b2, HB);

    // Layer 3
    k_gemm3<<<nbN, 256, 0, stream>>>(HB, W3, dis, t3);
    k_out<<<nbN, 256, 0, stream>>>(t3, rowptr, csr, dis, b3, out);
}

// Round 20
// 394.827 us; speedup vs baseline: 1.1218x; 1.1218x over previous
//
#include <hip/hip_runtime.h>
#include <math.h>

// N=100000 nodes, E=1600000 edges, features 128 -> 64 -> 64 -> 1.
// R20: ATOMIC-FREE csr scatter. R19 showed build_csr is bound by the 1.6M
// atomicAdd round-trips (int4 MLP didn't help; VALU 3%, BW 22%). k_hist's
// degree atomics already compute each edge's within-dst rank (the returned
// old value) — store it (erank), then scatter deterministically:
// csr[rowptr[dst]+erank] = src. No atomics, fire-and-forget stores.
// 4 dst-shards (slice 1.6MB, ~2 L2s) balance write-merging vs re-scan cost.
// NOTE: __launch_bounds__(256,4) is 0-for-4 on this harness — do not use.
// gemm2 K-loop needs `#pragma unroll 2` (full unroll -> 256 VGPR, occ 9%).
#define NN 100000
#define NE 1600000
#define NSHARD 4
#define SHARD_W (NN / NSHARD)   // 25000 exactly

// bf16 helpers (manual, round-to-nearest-even; intermediates only)
__device__ inline unsigned f2bf(float f) {
    unsigned u = __float_as_uint(f);
    u += 0x7FFFu + ((u >> 16) & 1u);
    return u >> 16;
}
__device__ inline float bflo(unsigned v) { return __uint_as_float(v << 16); }
__device__ inline float bfhi(unsigned v) { return __uint_as_float(v & 0xFFFF0000u); }

// ---------------------------------------------------------------------------
// CSR build: hist(+rank) -> block sums -> scan -> rowptr -> rank-scatter.
// ---------------------------------------------------------------------------
__global__ void k_zero_deg(int* __restrict__ deg) {
    int i = blockIdx.x * 256 + threadIdx.x;
    if (i < NN) deg[i] = 0;
}

// Degree histogram; atomicAdd's returned old value = edge's rank among
// edges with the same dst. Stored coalesced (int4).
__global__ void k_hist(const int4* __restrict__ dst4, int* __restrict__ deg,
                       int4* __restrict__ erank4) {
    int i = blockIdx.x * 256 + threadIdx.x;
    if (i < NE / 4) {
        int4 d = dst4[i];
        int4 r;
        r.x = atomicAdd(&deg[d.x], 1);
        r.y = atomicAdd(&deg[d.y], 1);
        r.z = atomicAdd(&deg[d.z], 1);
        r.w = atomicAdd(&deg[d.w], 1);
        erank4[i] = r;
    }
}

__global__ void k_bsum(const int* __restrict__ deg, int* __restrict__ bsums) {
    __shared__ int s[256];
    int t = threadIdx.x;
    int i = blockIdx.x * 256 + t;
    s[t] = (i < NN) ? deg[i] : 0;
    __syncthreads();
    for (int off = 128; off > 0; off >>= 1) {
        if (t < off) s[t] += s[t + off];
        __syncthreads();
    }
    if (t == 0) bsums[blockIdx.x] = s[0];
}

// single block of 512 threads scans the 391 block sums (exclusive)
__global__ void k_scan512(const int* __restrict__ bsums, int* __restrict__ bscan) {
    __shared__ int s[512];
    int t = threadIdx.x;
    int v = (t < 391) ? bsums[t] : 0;
    s[t] = v;
    __syncthreads();
    for (int off = 1; off < 512; off <<= 1) {
        int x = (t >= off) ? s[t - off] : 0;
        __syncthreads();
        s[t] += x;
        __syncthreads();
    }
    bscan[t] = s[t] - v;  // exclusive
}

__global__ void k_rowptr(const int* __restrict__ deg, const int* __restrict__ bscan,
                         int* __restrict__ rowptr, float* __restrict__ dis) {
    __shared__ int s[256];
    int t = threadIdx.x;
    int i = blockIdx.x * 256 + t;
    int d = (i < NN) ? deg[i] : 0;
    s[t] = d;
    __syncthreads();
    for (int off = 1; off < 256; off <<= 1) {
        int x = (t >= off) ? s[t - off] : 0;
        __syncthreads();
        s[t] += x;
        __syncthreads();
    }
    if (i < NN) {
        int rp = bscan[blockIdx.x] + s[t] - d;  // exclusive global prefix
        rowptr[i] = rp;
        dis[i] = rsqrtf((float)(d + 1));  // +1 self-loop; deg>=1 always
    }
    if (i == 0) rowptr[NN] = NE;
}

// Atomic-free sharded scatter: pos = rowptr[dst] + erank. Fire-and-forget
// stores; shard slice (1.6MB) merges in the (2) XCD L2s that write it.
__global__ __launch_bounds__(256) void k_build_csr(
    const int4* __restrict__ src4, const int4* __restrict__ dst4,
    const int4* __restrict__ erank4, const int* __restrict__ rowptr,
    int* __restrict__ csr) {
    int shard = blockIdx.x & (NSHARD - 1);
    int bsh = blockIdx.x >> 2;
    int stride = (gridDim.x >> 2) * 256;
    int lo = shard * SHARD_W;
    int hi = lo + SHARD_W;
    const int NE4 = NE / 4;
    for (int i = bsh * 256 + threadIdx.x; i < NE4; i += stride) {
        int4 d = dst4[i];
        int4 s = src4[i];
        int4 r = erank4[i];
        if (d.x >= lo && d.x < hi) csr[rowptr[d.x] + r.x] = s.x;
        if (d.y >= lo && d.y < hi) csr[rowptr[d.y] + r.y] = s.y;
        if (d.z >= lo && d.z < hi) csr[rowptr[d.z] + r.z] = s.z;
        if (d.w >= lo && d.w < hi) csr[rowptr[d.w] + r.w] = s.w;
    }
}

// ---------------------------------------------------------------------------
// GEMM layer 1: tsb[row][c] = bf16( (sum_k x[row][k]*W[k][c]) * dis[row] )
// 64 rows x 64 cols per block; thread = 4 rows x 4 cols register tile.
// W and x staged as packed bf16 PAIRS in LDS (one pass, one barrier).
// ---------------------------------------------------------------------------
__global__ __launch_bounds__(256) void k_gemm1(
    const float* __restrict__ x, const float* __restrict__ W,
    const float* __restrict__ dis, unsigned short* __restrict__ tsb) {
    __shared__ unsigned Wsb[128 * 32];
    __shared__ unsigned xsb[64 * 66];
    int t = threadIdx.x;
    int row0 = blockIdx.x * 64;
    for (int i = t; i < 128 * 32; i += 256) {
        int k = i >> 5, c2 = i & 31;
        float2 wv = *(const float2*)&W[k * 64 + 2 * c2];
        Wsb[i] = f2bf(wv.x) | (f2bf(wv.y) << 16);
    }
    for (int i = t; i < 64 * 64; i += 256) {
        int r = i >> 6, k2 = i & 63;
        int gr = row0 + r;
        unsigned p = 0u;
        if (gr < NN) {
            float2 xv = *(const float2*)&x[gr * 128 + 2 * k2];
            p = f2bf(xv.x) | (f2bf(xv.y) << 16);
        }
        xsb[r * 66 + k2] = p;
    }
    __syncthreads();
    int cg = t & 15, rg = t >> 4;
    int col = cg * 4;
    float4 acc0 = {0, 0, 0, 0}, acc1 = {0, 0, 0, 0}, acc2 = {0, 0, 0, 0}, acc3 = {0, 0, 0, 0};
    for (int k2 = 0; k2 < 64; ++k2) {
        uint2 wa = *(const uint2*)&Wsb[(2 * k2) * 32 + cg * 2];
        uint2 wb = *(const uint2*)&Wsb[(2 * k2 + 1) * 32 + cg * 2];
        float wa0 = bflo(wa.x), wa1 = bfhi(wa.x), wa2 = bflo(wa.y), wa3 = bfhi(wa.y);
        float wb0 = bflo(wb.x), wb1 = bfhi(wb.x), wb2 = bflo(wb.y), wb3 = bfhi(wb.y);
        unsigned xp0 = xsb[(rg * 4 + 0) * 66 + k2];
        unsigned xp1 = xsb[(rg * 4 + 1) * 66 + k2];
        unsigned xp2 = xsb[(rg * 4 + 2) * 66 + k2];
        unsigned xp3 = xsb[(rg * 4 + 3) * 66 + k2];
        float xl, xh;
        xl = bflo(xp0); xh = bfhi(xp0);
        acc0.x += xl * wa0 + xh * wb0; acc0.y += xl * wa1 + xh * wb1;
        acc0.z += xl * wa2 + xh * wb2; acc0.w += xl * wa3 + xh * wb3;
        xl = bflo(xp1); xh = bfhi(xp1);
        acc1.x += xl * wa0 + xh * wb0; acc1.y += xl * wa1 + xh * wb1;
        acc1.z += xl * wa2 + xh * wb2; acc1.w += xl * wa3 + xh * wb3;
        xl = bflo(xp2); xh = bfhi(xp2);
        acc2.x += xl * wa0 + xh * wb0; acc2.y += xl * wa1 + xh * wb1;
        acc2.z += xl * wa2 + xh * wb2; acc2.w += xl * wa3 + xh * wb3;
        xl = bflo(xp3); xh = bfhi(xp3);
        acc3.x += xl * wa0 + xh * wb0; acc3.y += xl * wa1 + xh * wb1;
        acc3.z += xl * wa2 + xh * wb2; acc3.w += xl * wa3 + xh * wb3;
    }
    float4 accs[4] = {acc0, acc1, acc2, acc3};
#pragma unroll
    for (int r = 0; r < 4; ++r) {
        int row = row0 + rg * 4 + r;
        if (row < NN) {
            float dv = dis[row];
            float4 a = accs[r];
            uint2 p;
            p.x = f2bf(a.x * dv) | (f2bf(a.y * dv) << 16);
            p.y = f2bf(a.z * dv) | (f2bf(a.w * dv) << 16);
            *(uint2*)&tsb[row * 64 + col] = p;
        }
    }
}

#define FMA4(acc, xv)                                              \
    acc.x += xv.x * w0.x + xv.y * w1.x + xv.z * w2.x + xv.w * w3.x; \
    acc.y += xv.x * w0.y + xv.y * w1.y + xv.z * w2.y + xv.w * w3.y; \
    acc.z += xv.x * w0.z + xv.y * w1.z + xv.z * w2.z + xv.w * w3.z; \
    acc.w += xv.x * w0.w + xv.y * w1.w + xv.z * w2.w + xv.w * w3.w;

// GEMM layer 2: reads bf16 h, writes bf16 ts. K=64.
// K-loop capped at unroll 2: full unroll balloons to 256 VGPR (R13).
__global__ __launch_bounds__(256) void k_gemm2(
    const unsigned short* __restrict__ hb, const float* __restrict__ W,
    const float* __restrict__ dis, unsigned short* __restrict__ tsb) {
    __shared__ float Ws[64 * 64];
    __shared__ float hs[64 * 68];
    int t = threadIdx.x;
    int row0 = blockIdx.x * 64;
    for (int i = t; i < 64 * 64; i += 256) Ws[i] = W[i];
    const unsigned* hb32 = (const unsigned*)hb;  // 2 bf16 per word, row stride 32
    for (int i = t; i < 64 * 32; i += 256) {
        int r = i >> 5, c2 = i & 31;
        int gr = row0 + r;
        unsigned v = (gr < NN) ? hb32[gr * 32 + c2] : 0u;
        hs[r * 68 + 2 * c2] = bflo(v);
        hs[r * 68 + 2 * c2 + 1] = bfhi(v);
    }
    __syncthreads();
    int cg = t & 15, rg = t >> 4;
    int col = cg * 4;
    float4 acc0 = {0, 0, 0, 0}, acc1 = {0, 0, 0, 0}, acc2 = {0, 0, 0, 0}, acc3 = {0, 0, 0, 0};
#pragma unroll 2
    for (int k = 0; k < 64; k += 4) {
        float4 w0 = *(const float4*)&Ws[(k + 0) * 64 + col];
        float4 w1 = *(const float4*)&Ws[(k + 1) * 64 + col];
        float4 w2 = *(const float4*)&Ws[(k + 2) * 64 + col];
        float4 w3 = *(const float4*)&Ws[(k + 3) * 64 + col];
        float4 x0 = *(const float4*)&hs[(rg * 4 + 0) * 68 + k];
        float4 x1 = *(const float4*)&hs[(rg * 4 + 1) * 68 + k];
        float4 x2 = *(const float4*)&hs[(rg * 4 + 2) * 68 + k];
        float4 x3 = *(const float4*)&hs[(rg * 4 + 3) * 68 + k];
        FMA4(acc0, x0) FMA4(acc1, x1) FMA4(acc2, x2) FMA4(acc3, x3)
    }
    float4 accs[4] = {acc0, acc1, acc2, acc3};
#pragma unroll
    for (int r = 0; r < 4; ++r) {
        int row = row0 + rg * 4 + r;
        if (row < NN) {
            float dv = dis[row];
            float4 a = accs[r];
            uint2 p;
            p.x = f2bf(a.x * dv) | (f2bf(a.y * dv) << 16);
            p.y = f2bf(a.z * dv) | (f2bf(a.w * dv) << 16);
            *(uint2*)&tsb[row * 64 + col] = p;
        }
    }
}

// ---------------------------------------------------------------------------
// Fused aggregation + dis scale + bias + ReLU, bf16 rows (128 B each).
// One 64-lane wave per node; QUARTER-wave (16 lanes x 8B) per edge -> 4
// edges in flight per load instruction. lane = feature QUAD (uint2 = 4 bf16).
// f32 accumulation; quads combined via shfl_xor(16) + shfl_xor(32).
// ---------------------------------------------------------------------------
__global__ __launch_bounds__(256) void k_agg_relu(
    const unsigned short* __restrict__ tsb, const int* __restrict__ rowptr,
    const int* __restrict__ csr, const float* __restrict__ dis,
    const float* __restrict__ b, unsigned short* __restrict__ hb) {
    int node = blockIdx.x * 4 + (threadIdx.x >> 6);
    if (node >= NN) return;
    int lane = threadIdx.x & 63;
    int q = lane >> 4;    // quarter 0..3
    int fl = lane & 15;   // feature quad: features 4*fl .. 4*fl+3
    const uint2* ts64 = (const uint2*)tsb;  // row stride 16 uint2
    float a0 = 0.f, a1 = 0.f, a2 = 0.f, a3 = 0.f;
    if (q == 0) {  // self-loop term, added once
        uint2 v = ts64[node * 16 + fl];
        a0 += bflo(v.x); a1 += bfhi(v.x); a2 += bflo(v.y); a3 += bfhi(v.y);
    }
    int e = rowptr[node] + q, end = rowptr[node + 1];
    // per-quarter stride 4; unroll 2 -> 8 edges in flight per wave
    for (; e + 4 < end; e += 8) {
        int s0 = csr[e];
        int s1 = csr[e + 4];
        uint2 v0 = ts64[s0 * 16 + fl];
        uint2 v1 = ts64[s1 * 16 + fl];
        a0 += bflo(v0.x) + bflo(v1.x);
        a1 += bfhi(v0.x) + bfhi(v1.x);
        a2 += bflo(v0.y) + bflo(v1.y);
        a3 += bfhi(v0.y) + bfhi(v1.y);
    }
    if (e < end) {
        uint2 v = ts64[csr[e] * 16 + fl];
        a0 += bflo(v.x); a1 += bfhi(v.x); a2 += bflo(v.y); a3 += bfhi(v.y);
    }
    a0 += __shfl_xor(a0, 16); a1 += __shfl_xor(a1, 16);
    a2 += __shfl_xor(a2, 16); a3 += __shfl_xor(a3, 16);
    a0 += __shfl_xor(a0, 32); a1 += __shfl_xor(a1, 32);
    a2 += __shfl_xor(a2, 32); a3 += __shfl_xor(a3, 32);
    if (q == 0) {
        float dv = dis[node];
        float v0 = fmaxf(a0 * dv + b[4 * fl + 0], 0.f);
        float v1 = fmaxf(a1 * dv + b[4 * fl + 1], 0.f);
        float v2 = fmaxf(a2 * dv + b[4 * fl + 2], 0.f);
        float v3 = fmaxf(a3 * dv + b[4 * fl + 3], 0.f);
        uint2 p;
        p.x = f2bf(v0) | (f2bf(v1) << 16);
        p.y = f2bf(v2) | (f2bf(v3) << 16);
        ((uint2*)hb)[node * 16 + fl] = p;
    }
}

// ---------------------------------------------------------------------------
// Layer 3 projection: t3[row] = dot(h_bf16[row], W3) * dis[row]   (f32 out)
// ---------------------------------------------------------------------------
__global__ void k_gemm3(const unsigned short* __restrict__ hb, const float* __restrict__ W3,
                        const float* __restrict__ dis, float* __restrict__ t3) {
    __shared__ float Ws[64];
    if (threadIdx.x < 64) Ws[threadIdx.x] = W3[threadIdx.x];
    __syncthreads();
    int row = blockIdx.x * 256 + threadIdx.x;
    if (row >= NN) return;
    const uint4* hp = (const uint4*)(hb + row * 64);  // 8 x uint4 = 128 B
    float acc = 0.f;
#pragma unroll
    for (int k = 0; k < 8; ++k) {
        uint4 v = hp[k];
        acc += bflo(v.x) * Ws[8 * k + 0] + bfhi(v.x) * Ws[8 * k + 1]
             + bflo(v.y) * Ws[8 * k + 2] + bfhi(v.y) * Ws[8 * k + 3]
             + bflo(v.z) * Ws[8 * k + 4] + bfhi(v.z) * Ws[8 * k + 5]
             + bflo(v.w) * Ws[8 * k + 6] + bfhi(v.w) * Ws[8 * k + 7];
    }
    t3[row] = acc * dis[row];
}

// Fused layer-3 aggregation + sigmoid. One thread per node, scalar gathers.
__global__ void k_out(const float* __restrict__ t3, const int* __restrict__ rowptr,
                      const int* __restrict__ csr, const float* __restrict__ dis,
                      const float* __restrict__ b3, float* __restrict__ out) {
    int i = blockIdx.x * 256 + threadIdx.x;
    if (i >= NN) return;
    float acc = t3[i];
    float acc1 = 0.f;
    int e = rowptr[i], end = rowptr[i + 1];
    for (; e + 2 <= end; e += 2) {
        acc += t3[csr[e]];
        acc1 += t3[csr[e + 1]];
    }
    if (e < end) acc += t3[csr[e]];
    float z = (acc + acc1) * dis[i] + b3[0];
    out[i] = 1.f / (1.f + __expf(-z));
}

// ---------------------------------------------------------------------------
extern "C" void kernel_launch(void* const* d_in, const int* in_sizes, int n_in,
                              void* d_out, int out_size, void* d_ws, size_t ws_size,
                              hipStream_t stream) {
    const float* x  = (const float*)d_in[0];   // N x 128
    const float* W1 = (const float*)d_in[1];   // 128 x 64
    const float* b1 = (const float*)d_in[2];   // 64
    const float* W2 = (const float*)d_in[3];   // 64 x 64
    const float* b2 = (const float*)d_in[4];   // 64
    const float* W3 = (const float*)d_in[5];   // 64 x 1
    const float* b3 = (const float*)d_in[6];   // 1
    const int*   ei = (const int*)d_in[7];     // 2 x E
    const int* src = ei;
    const int* dst = ei + NE;
    float* out = (float*)d_out;

    // Workspace layout
    unsigned short* TSB = (unsigned short*)d_ws;          // N*64 bf16 (ts)
    unsigned short* HB  = TSB + (size_t)NN * 64;          // N*64 bf16 (h)
    float* dis    = (float*)(HB + (size_t)NN * 64);       // N
    float* t3     = dis + NN;                             // N
    int*   deg    = (int*)(t3 + NN);                      // N
    int*   rowptr = deg + NN;                             // N+1 (+pad)
    int*   erank  = rowptr + NN + 8;                      // E
    int*   bsums  = erank + NE;                           // 512
    int*   bscan  = bsums + 512;                          // 512
    int*   csr    = bscan + 512;                          // E

    const int nbN = (NN + 255) / 256;       // 391
    const int nbE4 = (NE / 4 + 255) / 256;  // 1563
    const int nbG = (NN + 63) / 64;         // 1563
    const int nbA = (NN + 3) / 4;           // 25000

    // CSR build + normalization (rank recorded during histogram)
    k_zero_deg<<<nbN, 256, 0, stream>>>(deg);
    k_hist<<<nbE4, 256, 0, stream>>>((const int4*)dst, deg, (int4*)erank);
    k_bsum<<<nbN, 256, 0, stream>>>(deg, bsums);
    k_scan512<<<1, 512, 0, stream>>>(bsums, bscan);
    k_rowptr<<<nbN, 256, 0, stream>>>(deg, bscan, rowptr, dis);
    k_build_csr<<<2048, 256, 0, stream>>>((const int4*)src, (const int4*)dst,
                                          (const int4*)erank, rowptr, csr);

    // Layer 1
    k_gemm1<<<nbG, 256, 0, stream>>>(x, W1, dis, TSB);
    k_agg_relu<<<nbA, 256, 0, stream>>>(TSB, rowptr, csr, dis, b1, HB);

    // Layer 2
    k_gemm2<<<nbG, 256, 0, stream>>>(HB, W2, dis, TSB);
    k_agg_relu<<<nbA, 256, 0, stream>>>(TSB, rowptr, csr, dis, b2, HB);

    // Layer 3
    k_gemm3<<<nbN, 256, 0, stream>>>(HB, W3, dis, t3);
    k_out<<<nbN, 256, 0, stream>>>(t3, rowptr, csr, dis, b3, out);
}

// Round 21
// 386.671 us; speedup vs baseline: 1.1455x; 1.0211x over previous
//
#include <hip/hip_runtime.h>
#include <math.h>

// N=100000 nodes, E=1600000 edges, features 128 -> 64 -> 64 -> 1.
// R21 = R20 + eighth-wave k_agg_relu: 8 lanes x uint4(16B) per edge row ->
// 8 edges per load instruction, 16 in flight with unroll 2 (R18's quarter-
// wave had 4+4). Octets combined via shfl_xor(8/16/32) in the epilogue.
// Atomic floor note: any kernel doing 1.6M atomics to the 400KB node array
// costs ~68-72us (R15/R19/R20); exactly one such pass remains (k_hist).
// NOTE: __launch_bounds__(256,4) is 0-for-4 on this harness — do not use.
// gemm2 K-loop needs `#pragma unroll 2` (full unroll -> 256 VGPR, occ 9%).
#define NN 100000
#define NE 1600000
#define NSHARD 4
#define SHARD_W (NN / NSHARD)   // 25000 exactly

// bf16 helpers (manual, round-to-nearest-even; intermediates only)
__device__ inline unsigned f2bf(float f) {
    unsigned u = __float_as_uint(f);
    u += 0x7FFFu + ((u >> 16) & 1u);
    return u >> 16;
}
__device__ inline float bflo(unsigned v) { return __uint_as_float(v << 16); }
__device__ inline float bfhi(unsigned v) { return __uint_as_float(v & 0xFFFF0000u); }

// ---------------------------------------------------------------------------
// CSR build: hist(+rank) -> block sums -> scan -> rowptr -> rank-scatter.
// ---------------------------------------------------------------------------
__global__ void k_zero_deg(int* __restrict__ deg) {
    int i = blockIdx.x * 256 + threadIdx.x;
    if (i < NN) deg[i] = 0;
}

// Degree histogram; atomicAdd's returned old value = edge's rank among
// edges with the same dst. Stored coalesced (int4).
__global__ void k_hist(const int4* __restrict__ dst4, int* __restrict__ deg,
                       int4* __restrict__ erank4) {
    int i = blockIdx.x * 256 + threadIdx.x;
    if (i < NE / 4) {
        int4 d = dst4[i];
        int4 r;
        r.x = atomicAdd(&deg[d.x], 1);
        r.y = atomicAdd(&deg[d.y], 1);
        r.z = atomicAdd(&deg[d.z], 1);
        r.w = atomicAdd(&deg[d.w], 1);
        erank4[i] = r;
    }
}

__global__ void k_bsum(const int* __restrict__ deg, int* __restrict__ bsums) {
    __shared__ int s[256];
    int t = threadIdx.x;
    int i = blockIdx.x * 256 + t;
    s[t] = (i < NN) ? deg[i] : 0;
    __syncthreads();
    for (int off = 128; off > 0; off >>= 1) {
        if (t < off) s[t] += s[t + off];
        __syncthreads();
    }
    if (t == 0) bsums[blockIdx.x] = s[0];
}

// single block of 512 threads scans the 391 block sums (exclusive)
__global__ void k_scan512(const int* __restrict__ bsums, int* __restrict__ bscan) {
    __shared__ int s[512];
    int t = threadIdx.x;
    int v = (t < 391) ? bsums[t] : 0;
    s[t] = v;
    __syncthreads();
    for (int off = 1; off < 512; off <<= 1) {
        int x = (t >= off) ? s[t - off] : 0;
        __syncthreads();
        s[t] += x;
        __syncthreads();
    }
    bscan[t] = s[t] - v;  // exclusive
}

__global__ void k_rowptr(const int* __restrict__ deg, const int* __restrict__ bscan,
                         int* __restrict__ rowptr, float* __restrict__ dis) {
    __shared__ int s[256];
    int t = threadIdx.x;
    int i = blockIdx.x * 256 + t;
    int d = (i < NN) ? deg[i] : 0;
    s[t] = d;
    __syncthreads();
    for (int off = 1; off < 256; off <<= 1) {
        int x = (t >= off) ? s[t - off] : 0;
        __syncthreads();
        s[t] += x;
        __syncthreads();
    }
    if (i < NN) {
        int rp = bscan[blockIdx.x] + s[t] - d;  // exclusive global prefix
        rowptr[i] = rp;
        dis[i] = rsqrtf((float)(d + 1));  // +1 self-loop; deg>=1 always
    }
    if (i == 0) rowptr[NN] = NE;
}

// Atomic-free sharded scatter: pos = rowptr[dst] + erank. Fire-and-forget
// stores; shard slice (1.6MB) merges in the (2) XCD L2s that write it.
__global__ __launch_bounds__(256) void k_build_csr(
    const int4* __restrict__ src4, const int4* __restrict__ dst4,
    const int4* __restrict__ erank4, const int* __restrict__ rowptr,
    int* __restrict__ csr) {
    int shard = blockIdx.x & (NSHARD - 1);
    int bsh = blockIdx.x >> 2;
    int stride = (gridDim.x >> 2) * 256;
    int lo = shard * SHARD_W;
    int hi = lo + SHARD_W;
    const int NE4 = NE / 4;
    for (int i = bsh * 256 + threadIdx.x; i < NE4; i += stride) {
        int4 d = dst4[i];
        int4 s = src4[i];
        int4 r = erank4[i];
        if (d.x >= lo && d.x < hi) csr[rowptr[d.x] + r.x] = s.x;
        if (d.y >= lo && d.y < hi) csr[rowptr[d.y] + r.y] = s.y;
        if (d.z >= lo && d.z < hi) csr[rowptr[d.z] + r.z] = s.z;
        if (d.w >= lo && d.w < hi) csr[rowptr[d.w] + r.w] = s.w;
    }
}

// ---------------------------------------------------------------------------
// GEMM layer 1: tsb[row][c] = bf16( (sum_k x[row][k]*W[k][c]) * dis[row] )
// 64 rows x 64 cols per block; thread = 4 rows x 4 cols register tile.
// W and x staged as packed bf16 PAIRS in LDS (one pass, one barrier).
// ---------------------------------------------------------------------------
__global__ __launch_bounds__(256) void k_gemm1(
    const float* __restrict__ x, const float* __restrict__ W,
    const float* __restrict__ dis, unsigned short* __restrict__ tsb) {
    __shared__ unsigned Wsb[128 * 32];
    __shared__ unsigned xsb[64 * 66];
    int t = threadIdx.x;
    int row0 = blockIdx.x * 64;
    for (int i = t; i < 128 * 32; i += 256) {
        int k = i >> 5, c2 = i & 31;
        float2 wv = *(const float2*)&W[k * 64 + 2 * c2];
        Wsb[i] = f2bf(wv.x) | (f2bf(wv.y) << 16);
    }
    for (int i = t; i < 64 * 64; i += 256) {
        int r = i >> 6, k2 = i & 63;
        int gr = row0 + r;
        unsigned p = 0u;
        if (gr < NN) {
            float2 xv = *(const float2*)&x[gr * 128 + 2 * k2];
            p = f2bf(xv.x) | (f2bf(xv.y) << 16);
        }
        xsb[r * 66 + k2] = p;
    }
    __syncthreads();
    int cg = t & 15, rg = t >> 4;
    int col = cg * 4;
    float4 acc0 = {0, 0, 0, 0}, acc1 = {0, 0, 0, 0}, acc2 = {0, 0, 0, 0}, acc3 = {0, 0, 0, 0};
    for (int k2 = 0; k2 < 64; ++k2) {
        uint2 wa = *(const uint2*)&Wsb[(2 * k2) * 32 + cg * 2];
        uint2 wb = *(const uint2*)&Wsb[(2 * k2 + 1) * 32 + cg * 2];
        float wa0 = bflo(wa.x), wa1 = bfhi(wa.x), wa2 = bflo(wa.y), wa3 = bfhi(wa.y);
        float wb0 = bflo(wb.x), wb1 = bfhi(wb.x), wb2 = bflo(wb.y), wb3 = bfhi(wb.y);
        unsigned xp0 = xsb[(rg * 4 + 0) * 66 + k2];
        unsigned xp1 = xsb[(rg * 4 + 1) * 66 + k2];
        unsigned xp2 = xsb[(rg * 4 + 2) * 66 + k2];
        unsigned xp3 = xsb[(rg * 4 + 3) * 66 + k2];
        float xl, xh;
        xl = bflo(xp0); xh = bfhi(xp0);
        acc0.x += xl * wa0 + xh * wb0; acc0.y += xl * wa1 + xh * wb1;
        acc0.z += xl * wa2 + xh * wb2; acc0.w += xl * wa3 + xh * wb3;
        xl = bflo(xp1); xh = bfhi(xp1);
        acc1.x += xl * wa0 + xh * wb0; acc1.y += xl * wa1 + xh * wb1;
        acc1.z += xl * wa2 + xh * wb2; acc1.w += xl * wa3 + xh * wb3;
        xl = bflo(xp2); xh = bfhi(xp2);
        acc2.x += xl * wa0 + xh * wb0; acc2.y += xl * wa1 + xh * wb1;
        acc2.z += xl * wa2 + xh * wb2; acc2.w += xl * wa3 + xh * wb3;
        xl = bflo(xp3); xh = bfhi(xp3);
        acc3.x += xl * wa0 + xh * wb0; acc3.y += xl * wa1 + xh * wb1;
        acc3.z += xl * wa2 + xh * wb2; acc3.w += xl * wa3 + xh * wb3;
    }
    float4 accs[4] = {acc0, acc1, acc2, acc3};
#pragma unroll
    for (int r = 0; r < 4; ++r) {
        int row = row0 + rg * 4 + r;
        if (row < NN) {
            float dv = dis[row];
            float4 a = accs[r];
            uint2 p;
            p.x = f2bf(a.x * dv) | (f2bf(a.y * dv) << 16);
            p.y = f2bf(a.z * dv) | (f2bf(a.w * dv) << 16);
            *(uint2*)&tsb[row * 64 + col] = p;
        }
    }
}

#define FMA4(acc, xv)                                              \
    acc.x += xv.x * w0.x + xv.y * w1.x + xv.z * w2.x + xv.w * w3.x; \
    acc.y += xv.x * w0.y + xv.y * w1.y + xv.z * w2.y + xv.w * w3.y; \
    acc.z += xv.x * w0.z + xv.y * w1.z + xv.z * w2.z + xv.w * w3.z; \
    acc.w += xv.x * w0.w + xv.y * w1.w + xv.z * w2.w + xv.w * w3.w;

// GEMM layer 2: reads bf16 h, writes bf16 ts. K=64.
// K-loop capped at unroll 2: full unroll balloons to 256 VGPR (R13).
__global__ __launch_bounds__(256) void k_gemm2(
    const unsigned short* __restrict__ hb, const float* __restrict__ W,
    const float* __restrict__ dis, unsigned short* __restrict__ tsb) {
    __shared__ float Ws[64 * 64];
    __shared__ float hs[64 * 68];
    int t = threadIdx.x;
    int row0 = blockIdx.x * 64;
    for (int i = t; i < 64 * 64; i += 256) Ws[i] = W[i];
    const unsigned* hb32 = (const unsigned*)hb;  // 2 bf16 per word, row stride 32
    for (int i = t; i < 64 * 32; i += 256) {
        int r = i >> 5, c2 = i & 31;
        int gr = row0 + r;
        unsigned v = (gr < NN) ? hb32[gr * 32 + c2] : 0u;
        hs[r * 68 + 2 * c2] = bflo(v);
        hs[r * 68 + 2 * c2 + 1] = bfhi(v);
    }
    __syncthreads();
    int cg = t & 15, rg = t >> 4;
    int col = cg * 4;
    float4 acc0 = {0, 0, 0, 0}, acc1 = {0, 0, 0, 0}, acc2 = {0, 0, 0, 0}, acc3 = {0, 0, 0, 0};
#pragma unroll 2
    for (int k = 0; k < 64; k += 4) {
        float4 w0 = *(const float4*)&Ws[(k + 0) * 64 + col];
        float4 w1 = *(const float4*)&Ws[(k + 1) * 64 + col];
        float4 w2 = *(const float4*)&Ws[(k + 2) * 64 + col];
        float4 w3 = *(const float4*)&Ws[(k + 3) * 64 + col];
        float4 x0 = *(const float4*)&hs[(rg * 4 + 0) * 68 + k];
        float4 x1 = *(const float4*)&hs[(rg * 4 + 1) * 68 + k];
        float4 x2 = *(const float4*)&hs[(rg * 4 + 2) * 68 + k];
        float4 x3 = *(const float4*)&hs[(rg * 4 + 3) * 68 + k];
        FMA4(acc0, x0) FMA4(acc1, x1) FMA4(acc2, x2) FMA4(acc3, x3)
    }
    float4 accs[4] = {acc0, acc1, acc2, acc3};
#pragma unroll
    for (int r = 0; r < 4; ++r) {
        int row = row0 + rg * 4 + r;
        if (row < NN) {
            float dv = dis[row];
            float4 a = accs[r];
            uint2 p;
            p.x = f2bf(a.x * dv) | (f2bf(a.y * dv) << 16);
            p.y = f2bf(a.z * dv) | (f2bf(a.w * dv) << 16);
            *(uint2*)&tsb[row * 64 + col] = p;
        }
    }
}

// ---------------------------------------------------------------------------
// Fused aggregation + dis scale + bias + ReLU, bf16 rows (128 B each).
// One 64-lane wave per node; EIGHTH-wave (8 lanes x 16B uint4) per edge ->
// 8 edges per load instruction, 16 in flight with unroll 2. lane = feature
// OCTET (uint4 = 8 bf16). f32 accum; octets combined via shfl_xor(8/16/32).
// ---------------------------------------------------------------------------
__global__ __launch_bounds__(256) void k_agg_relu(
    const unsigned short* __restrict__ tsb, const int* __restrict__ rowptr,
    const int* __restrict__ csr, const float* __restrict__ dis,
    const float* __restrict__ b, unsigned short* __restrict__ hb) {
    int node = blockIdx.x * 4 + (threadIdx.x >> 6);
    if (node >= NN) return;
    int lane = threadIdx.x & 63;
    int oct = lane >> 3;  // octet 0..7
    int fl = lane & 7;    // feature octet: features 8*fl .. 8*fl+7
    const uint4* ts128 = (const uint4*)tsb;  // row stride 8 uint4
    float a0 = 0.f, a1 = 0.f, a2 = 0.f, a3 = 0.f, a4 = 0.f, a5 = 0.f, a6 = 0.f, a7 = 0.f;
    if (oct == 0) {  // self-loop term, added once
        uint4 v = ts128[node * 8 + fl];
        a0 += bflo(v.x); a1 += bfhi(v.x); a2 += bflo(v.y); a3 += bfhi(v.y);
        a4 += bflo(v.z); a5 += bfhi(v.z); a6 += bflo(v.w); a7 += bfhi(v.w);
    }
    int e = rowptr[node] + oct, end = rowptr[node + 1];
    // per-octet stride 8; unroll 2 -> 16 edges in flight per wave
    for (; e + 8 < end; e += 16) {
        int s0 = csr[e];
        int s1 = csr[e + 8];
        uint4 v0 = ts128[s0 * 8 + fl];
        uint4 v1 = ts128[s1 * 8 + fl];
        a0 += bflo(v0.x) + bflo(v1.x); a1 += bfhi(v0.x) + bfhi(v1.x);
        a2 += bflo(v0.y) + bflo(v1.y); a3 += bfhi(v0.y) + bfhi(v1.y);
        a4 += bflo(v0.z) + bflo(v1.z); a5 += bfhi(v0.z) + bfhi(v1.z);
        a6 += bflo(v0.w) + bflo(v1.w); a7 += bfhi(v0.w) + bfhi(v1.w);
    }
    if (e < end) {
        uint4 v = ts128[csr[e] * 8 + fl];
        a0 += bflo(v.x); a1 += bfhi(v.x); a2 += bflo(v.y); a3 += bfhi(v.y);
        a4 += bflo(v.z); a5 += bfhi(v.z); a6 += bflo(v.w); a7 += bfhi(v.w);
    }
#pragma unroll
    for (int off = 8; off <= 32; off <<= 1) {
        a0 += __shfl_xor(a0, off); a1 += __shfl_xor(a1, off);
        a2 += __shfl_xor(a2, off); a3 += __shfl_xor(a3, off);
        a4 += __shfl_xor(a4, off); a5 += __shfl_xor(a5, off);
        a6 += __shfl_xor(a6, off); a7 += __shfl_xor(a7, off);
    }
    if (oct == 0) {
        float dv = dis[node];
        float v0 = fmaxf(a0 * dv + b[8 * fl + 0], 0.f);
        float v1 = fmaxf(a1 * dv + b[8 * fl + 1], 0.f);
        float v2 = fmaxf(a2 * dv + b[8 * fl + 2], 0.f);
        float v3 = fmaxf(a3 * dv + b[8 * fl + 3], 0.f);
        float v4 = fmaxf(a4 * dv + b[8 * fl + 4], 0.f);
        float v5 = fmaxf(a5 * dv + b[8 * fl + 5], 0.f);
        float v6 = fmaxf(a6 * dv + b[8 * fl + 6], 0.f);
        float v7 = fmaxf(a7 * dv + b[8 * fl + 7], 0.f);
        uint4 p;
        p.x = f2bf(v0) | (f2bf(v1) << 16);
        p.y = f2bf(v2) | (f2bf(v3) << 16);
        p.z = f2bf(v4) | (f2bf(v5) << 16);
        p.w = f2bf(v6) | (f2bf(v7) << 16);
        ((uint4*)hb)[node * 8 + fl] = p;
    }
}

// ---------------------------------------------------------------------------
// Layer 3 projection: t3[row] = dot(h_bf16[row], W3) * dis[row]   (f32 out)
// ---------------------------------------------------------------------------
__global__ void k_gemm3(const unsigned short* __restrict__ hb, const float* __restrict__ W3,
                        const float* __restrict__ dis, float* __restrict__ t3) {
    __shared__ float Ws[64];
    if (threadIdx.x < 64) Ws[threadIdx.x] = W3[threadIdx.x];
    __syncthreads();
    int row = blockIdx.x * 256 + threadIdx.x;
    if (row >= NN) return;
    const uint4* hp = (const uint4*)(hb + row * 64);  // 8 x uint4 = 128 B
    float acc = 0.f;
#pragma unroll
    for (int k = 0; k < 8; ++k) {
        uint4 v = hp[k];
        acc += bflo(v.x) * Ws[8 * k + 0] + bfhi(v.x) * Ws[8 * k + 1]
             + bflo(v.y) * Ws[8 * k + 2] + bfhi(v.y) * Ws[8 * k + 3]
             + bflo(v.z) * Ws[8 * k + 4] + bfhi(v.z) * Ws[8 * k + 5]
             + bflo(v.w) * Ws[8 * k + 6] + bfhi(v.w) * Ws[8 * k + 7];
    }
    t3[row] = acc * dis[row];
}

// Fused layer-3 aggregation + sigmoid. One thread per node; unroll 4.
__global__ void k_out(const float* __restrict__ t3, const int* __restrict__ rowptr,
                      const int* __restrict__ csr, const float* __restrict__ dis,
                      const float* __restrict__ b3, float* __restrict__ out) {
    int i = blockIdx.x * 256 + threadIdx.x;
    if (i >= NN) return;
    float acc = t3[i];
    float acc1 = 0.f, acc2 = 0.f, acc3 = 0.f;
    int e = rowptr[i], end = rowptr[i + 1];
    for (; e + 4 <= end; e += 4) {
        acc += t3[csr[e]];
        acc1 += t3[csr[e + 1]];
        acc2 += t3[csr[e + 2]];
        acc3 += t3[csr[e + 3]];
    }
    for (; e < end; ++e) acc += t3[csr[e]];
    float z = ((acc + acc1) + (acc2 + acc3)) * dis[i] + b3[0];
    out[i] = 1.f / (1.f + __expf(-z));
}

// ---------------------------------------------------------------------------
extern "C" void kernel_launch(void* const* d_in, const int* in_sizes, int n_in,
                              void* d_out, int out_size, void* d_ws, size_t ws_size,
                              hipStream_t stream) {
    const float* x  = (const float*)d_in[0];   // N x 128
    const float* W1 = (const float*)d_in[1];   // 128 x 64
    const float* b1 = (const float*)d_in[2];   // 64
    const float* W2 = (const float*)d_in[3];   // 64 x 64
    const float* b2 = (const float*)d_in[4];   // 64
    const float* W3 = (const float*)d_in[5];   // 64 x 1
    const float* b3 = (const float*)d_in[6];   // 1
    const int*   ei = (const int*)d_in[7];     // 2 x E
    const int* src = ei;
    const int* dst = ei + NE;
    float* out = (float*)d_out;

    // Workspace layout
    unsigned short* TSB = (unsigned short*)d_ws;          // N*64 bf16 (ts)
    unsigned short* HB  = TSB + (size_t)NN * 64;          // N*64 bf16 (h)
    float* dis    = (float*)(HB + (size_t)NN * 64);       // N
    float* t3     = dis + NN;                             // N
    int*   deg    = (int*)(t3 + NN);                      // N
    int*   rowptr = deg + NN;                             // N+1 (+pad)
    int*   erank  = rowptr + NN + 8;                      // E
    int*   bsums  = erank + NE;                           // 512
    int*   bscan  = bsums + 512;                          // 512
    int*   csr    = bscan + 512;                          // E

    const int nbN = (NN + 255) / 256;       // 391
    const int nbE4 = (NE / 4 + 255) / 256;  // 1563
    const int nbG = (NN + 63) / 64;         // 1563
    const int nbA = (NN + 3) / 4;           // 25000

    // CSR build + normalization (rank recorded during histogram)
    k_zero_deg<<<nbN, 256, 0, stream>>>(deg);
    k_hist<<<nbE4, 256, 0, stream>>>((const int4*)dst, deg, (int4*)erank);
    k_bsum<<<nbN, 256, 0, stream>>>(deg, bsums);
    k_scan512<<<1, 512, 0, stream>>>(bsums, bscan);
    k_rowptr<<<nbN, 256, 0, stream>>>(deg, bscan, rowptr, dis);
    k_build_csr<<<2048, 256, 0, stream>>>((const int4*)src, (const int4*)dst,
                                          (const int4*)erank, rowptr, csr);

    // Layer 1
    k_gemm1<<<nbG, 256, 0, stream>>>(x, W1, dis, TSB);
    k_agg_relu<<<nbA, 256, 0, stream>>>(TSB, rowptr, csr, dis, b1, HB);

    // Layer 2
    k_gemm2<<<nbG, 256, 0, stream>>>(HB, W2, dis, TSB);
    k_agg_relu<<<nbA, 256, 0, stream>>>(TSB, rowptr, csr, dis, b2, HB);

    // Layer 3
    k_gemm3<<<nbN, 256, 0, stream>>>(HB, W3, dis, t3);
    k_out<<<nbN, 256, 0, stream>>>(t3, rowptr, csr, dis, b3, out);
}